// Round 1
// baseline (1345.990 us; speedup 1.0000x reference)
//
#include <hip/hip_runtime.h>
#include <cstdint>
#include <cstddef>

#define DEVI __device__ __forceinline__

typedef __attribute__((ext_vector_type(8))) short short8;
typedef __attribute__((ext_vector_type(4))) float f32x4;

DEVI unsigned short f2b(float f) {
  unsigned int u = __float_as_uint(f);
  unsigned int r = (u + 0x7FFFu + ((u >> 16) & 1u)) >> 16;  // round-to-nearest-even
  return (unsigned short)r;
}

// ---------------- f32 -> bf16 convert (weights) ----------------
__global__ void convert_bf16_kernel(const float* __restrict__ in,
                                    unsigned short* __restrict__ out, int n4) {
  int i = blockIdx.x * blockDim.x + threadIdx.x;
  if (i >= n4) return;
  const float4 v = ((const float4*)in)[i];
  ushort4 o;
  o.x = f2b(v.x); o.y = f2b(v.y); o.z = f2b(v.z); o.w = f2b(v.w);
  ((ushort4*)out)[i] = o;
}

// ---------------- time-mix (k,v,r) + bf16 cast ----------------
__global__ void mix3_kernel(const float* __restrict__ x,
                            const float* __restrict__ tmk,
                            const float* __restrict__ tmv,
                            const float* __restrict__ tmr,
                            unsigned short* __restrict__ kin,
                            unsigned short* __restrict__ vin,
                            unsigned short* __restrict__ rin,
                            int T, int C, long n4) {
  long i = (long)blockIdx.x * blockDim.x + threadIdx.x;
  const long stride = (long)gridDim.x * blockDim.x;
  for (; i < n4; i += stride) {
    const long e = i * 4;
    const int c = (int)(e % C);
    const int t = (int)((e / C) % T);
    float4 xv = *(const float4*)(x + e);
    float4 pv = {0.f, 0.f, 0.f, 0.f};
    if (t > 0) pv = *(const float4*)(x + e - C);
    const float4 mk = *(const float4*)(tmk + c);
    const float4 mv = *(const float4*)(tmv + c);
    const float4 mr = *(const float4*)(tmr + c);
    const float* xp = (const float*)&xv;
    const float* pp = (const float*)&pv;
    const float* mkp = (const float*)&mk;
    const float* mvp = (const float*)&mv;
    const float* mrp = (const float*)&mr;
    ushort4 ko, vo, ro;
    unsigned short* kop = (unsigned short*)&ko;
    unsigned short* vop = (unsigned short*)&vo;
    unsigned short* rop = (unsigned short*)&ro;
#pragma unroll
    for (int q = 0; q < 4; ++q) {
      kop[q] = f2b(xp[q] * mkp[q] + pp[q] * (1.f - mkp[q]));
      vop[q] = f2b(xp[q] * mvp[q] + pp[q] * (1.f - mvp[q]));
      rop[q] = f2b(xp[q] * mrp[q] + pp[q] * (1.f - mrp[q]));
    }
    *(ushort4*)(kin + e) = ko;
    *(ushort4*)(vin + e) = vo;
    *(ushort4*)(rin + e) = ro;
  }
}

// ---------------- bf16 GEMM: C[M][N] = A[M][K] * W[N][K]^T ----------------
// m97 structure: 128x128 tile, BK=32, 4 waves (2x2), global_load_lds width=16,
// 16x16x32 bf16 MFMA, f32 accumulate/output.
__global__ __launch_bounds__(256)
void gemm_bf16_bt(const unsigned short* __restrict__ A,
                  const unsigned short* __restrict__ W,
                  float* __restrict__ C_out,
                  int M, int N, int K) {
  constexpr int BM = 128, BN = 128, BK = 32;
  __shared__ alignas(16) unsigned short As[BM * BK];
  __shared__ alignas(16) unsigned short Bs[BN * BK];
  const int m0 = blockIdx.x * BM;
  const int n0 = blockIdx.y * BN;
  const int tid = threadIdx.x;
  const int lane = tid & 63;
  const int w = tid >> 6;
  const int wr = w >> 1, wc = w & 1;     // 2x2 wave grid, each wave 64x64
  const int fr = lane & 15;              // fragment row/col within 16
  const int fk = (lane >> 4) * 8;        // fragment K offset (8 contiguous)

  f32x4 acc[4][4];
#pragma unroll
  for (int i = 0; i < 4; ++i)
#pragma unroll
    for (int j = 0; j < 4; ++j) acc[i][j] = (f32x4){0.f, 0.f, 0.f, 0.f};

  for (int kt = 0; kt < K; kt += BK) {
    // Stage A and B tiles: each 128x32 bf16 = 8KB = 512 x 16B chunks.
    // Wave w covers chunks [w*128, w*128+128) in 2 calls of 64 lanes.
#pragma unroll
    for (int j = 0; j < 2; ++j) {
      const int chunk = (w * 2 + j) * 64 + lane;  // 0..511
      const int row = chunk >> 2, cc = chunk & 3;
      const unsigned short* gsrcA = A + (size_t)(m0 + row) * K + kt + cc * 8;
      __builtin_amdgcn_global_load_lds(
          (const __attribute__((address_space(1))) void*)gsrcA,
          (__attribute__((address_space(3))) void*)&As[(w * 2 + j) * 512],
          16, 0, 0);
      const unsigned short* gsrcB = W + (size_t)(n0 + row) * K + kt + cc * 8;
      __builtin_amdgcn_global_load_lds(
          (const __attribute__((address_space(1))) void*)gsrcB,
          (__attribute__((address_space(3))) void*)&Bs[(w * 2 + j) * 512],
          16, 0, 0);
    }
    __syncthreads();  // drains vmcnt before barrier

    short8 af[4], bfr[4];
#pragma unroll
    for (int i = 0; i < 4; ++i) {
      af[i]  = *(const short8*)&As[(wr * 64 + i * 16 + fr) * BK + fk];
      bfr[i] = *(const short8*)&Bs[(wc * 64 + i * 16 + fr) * BK + fk];
    }
#pragma unroll
    for (int i = 0; i < 4; ++i)
#pragma unroll
      for (int j = 0; j < 4; ++j)
        acc[i][j] = __builtin_amdgcn_mfma_f32_16x16x32_bf16(af[i], bfr[j],
                                                            acc[i][j], 0, 0, 0);
    __syncthreads();
  }

  // C/D layout (m89-verified): col = lane&15, row = (lane>>4)*4 + reg
  const int orow = (lane >> 4) * 4;
  const int ocol = lane & 15;
#pragma unroll
  for (int i = 0; i < 4; ++i)
#pragma unroll
    for (int j = 0; j < 4; ++j) {
      const size_t rbase = (size_t)(m0 + wr * 64 + i * 16 + orow);
      const int cb = n0 + wc * 64 + j * 16 + ocol;
#pragma unroll
      for (int q = 0; q < 4; ++q)
        C_out[(rbase + q) * N + cb] = acc[i][j][q];
    }
}

// ---------------- WKV sequential scan + sigmoid gate ----------------
__global__ void wkv_kernel(const float* __restrict__ key,
                           const float* __restrict__ val,
                           const float* __restrict__ rec,
                           const float* __restrict__ td,
                           const float* __restrict__ tf,
                           unsigned short* __restrict__ rwkv,
                           int T, int C) {
  const int g = blockIdx.x * blockDim.x + threadIdx.x;  // 0..B*C-1
  const int c = g & (C - 1);
  const int b = g / C;
  const float w = -__expf(td[c]);
  const float u = tf[c];
  float num = 0.f, den = 0.f, mx = -1e38f;
  size_t idx = (size_t)b * T * C + c;
  for (int t = 0; t < T; ++t, idx += C) {
    const float kt = key[idx];
    const float vt = val[idx];
    const float rt = rec[idx];
    const float ku = kt + u;
    const float mo = fmaxf(mx, ku);
    const float e1 = __expf(mx - mo);
    const float e2 = __expf(ku - mo);
    const float out = (e1 * num + e2 * vt) / (e1 * den + e2);
    const float sr = 1.f / (1.f + __expf(-rt));
    rwkv[idx] = f2b(sr * out);
    const float mw = mx + w;
    const float mn = fmaxf(mw, kt);
    const float a1 = __expf(mw - mn);
    const float a2 = __expf(kt - mn);
    num = a1 * num + a2 * vt;
    den = a1 * den + a2;
    mx = mn;
  }
}

extern "C" void kernel_launch(void* const* d_in, const int* in_sizes, int n_in,
                              void* d_out, int out_size, void* d_ws, size_t ws_size,
                              hipStream_t stream) {
  const float* x   = (const float*)d_in[0];
  const float* Wk  = (const float*)d_in[1];
  const float* Wv  = (const float*)d_in[2];
  const float* Wr  = (const float*)d_in[3];
  const float* Wo  = (const float*)d_in[4];
  const float* td  = (const float*)d_in[5];
  const float* tf  = (const float*)d_in[6];
  const float* tmk = (const float*)d_in[7];
  const float* tmv = (const float*)d_in[8];
  const float* tmr = (const float*)d_in[9];

  const int B = 8, T = 2048, C = 1024;
  const long BT = (long)B * T;       // 16384
  const long NE = BT * C;            // 16,777,216
  const long CC = (long)C * C;       // 1,048,576

  // Workspace carve (~232 MB total)
  char* p = (char*)d_ws;
  unsigned short* Wk_b = (unsigned short*)p; p += CC * 2;
  unsigned short* Wv_b = (unsigned short*)p; p += CC * 2;
  unsigned short* Wr_b = (unsigned short*)p; p += CC * 2;
  unsigned short* Wo_b = (unsigned short*)p; p += CC * 2;
  unsigned short* kin  = (unsigned short*)p; p += NE * 2;
  unsigned short* vin  = (unsigned short*)p; p += NE * 2;
  unsigned short* rin  = (unsigned short*)p; p += NE * 2;
  float* keyf = (float*)p; p += NE * 4;
  float* valf = (float*)p; p += NE * 4;
  // receptance f32 lives in d_out (dead before final GEMM overwrites it)
  float* recf = (float*)d_out;
  unsigned short* rwkv = rin;  // rin dead after receptance GEMM

  // 1. weights -> bf16
  {
    const int n4 = (int)(CC / 4);
    dim3 g((n4 + 255) / 256), b_(256);
    convert_bf16_kernel<<<g, b_, 0, stream>>>(Wk, Wk_b, n4);
    convert_bf16_kernel<<<g, b_, 0, stream>>>(Wv, Wv_b, n4);
    convert_bf16_kernel<<<g, b_, 0, stream>>>(Wr, Wr_b, n4);
    convert_bf16_kernel<<<g, b_, 0, stream>>>(Wo, Wo_b, n4);
  }

  // 2. time-mix + cast
  {
    const long n4 = NE / 4;
    mix3_kernel<<<2048, 256, 0, stream>>>(x, tmk, tmv, tmr, kin, vin, rin, T, C, n4);
  }

  // 3. QKV-style GEMMs
  {
    dim3 grid((unsigned)(BT / 128), (unsigned)(C / 128)), blk(256);
    gemm_bf16_bt<<<grid, blk, 0, stream>>>(kin, Wk_b, keyf, (int)BT, C, C);
    gemm_bf16_bt<<<grid, blk, 0, stream>>>(vin, Wv_b, valf, (int)BT, C, C);
    gemm_bf16_bt<<<grid, blk, 0, stream>>>(rin, Wr_b, recf, (int)BT, C, C);
  }

  // 4. WKV scan + sigmoid gate -> rwkv bf16
  wkv_kernel<<<128, 64, 0, stream>>>(keyf, valf, recf, td, tf, rwkv, T, C);

  // 5. output GEMM -> d_out
  {
    dim3 grid((unsigned)(BT / 128), (unsigned)(C / 128)), blk(256);
    gemm_bf16_bt<<<grid, blk, 0, stream>>>(rwkv, Wo_b, (float*)d_out, (int)BT, C, C);
  }
}

// Round 2
// 411.448 us; speedup vs baseline: 3.2714x; 3.2714x over previous
//
#include <hip/hip_runtime.h>
#include <cstdint>
#include <cstddef>

#define DEVI __device__ __forceinline__

typedef __attribute__((ext_vector_type(8))) short short8;
typedef __attribute__((ext_vector_type(4))) float f32x4;

constexpr int Bc = 8, Tc = 2048, Cc = 1024;
constexpr int WKV_L = 32, WKV_NCH = 64;   // T = L * NCH

DEVI unsigned short f2b(float f) {
  unsigned int u = __float_as_uint(f);
  unsigned int r = (u + 0x7FFFu + ((u >> 16) & 1u)) >> 16;  // round-to-nearest-even
  return (unsigned short)r;
}

// ---------------- f32 -> bf16 convert (weights) ----------------
__global__ void convert_bf16_kernel(const float* __restrict__ in,
                                    unsigned short* __restrict__ out, int n4) {
  int i = blockIdx.x * blockDim.x + threadIdx.x;
  if (i >= n4) return;
  const float4 v = ((const float4*)in)[i];
  ushort4 o;
  o.x = f2b(v.x); o.y = f2b(v.y); o.z = f2b(v.z); o.w = f2b(v.w);
  ((ushort4*)out)[i] = o;
}

// ---------------- time-mix (k,v,r) + bf16 cast ----------------
__global__ void mix3_kernel(const float* __restrict__ x,
                            const float* __restrict__ tmk,
                            const float* __restrict__ tmv,
                            const float* __restrict__ tmr,
                            unsigned short* __restrict__ kin,
                            unsigned short* __restrict__ vin,
                            unsigned short* __restrict__ rin,
                            long n4) {
  long i = (long)blockIdx.x * blockDim.x + threadIdx.x;
  const long stride = (long)gridDim.x * blockDim.x;
  for (; i < n4; i += stride) {
    const long e = i * 4;
    const int c = (int)(e % Cc);
    const int t = (int)((e / Cc) % Tc);
    float4 xv = *(const float4*)(x + e);
    float4 pv = {0.f, 0.f, 0.f, 0.f};
    if (t > 0) pv = *(const float4*)(x + e - Cc);
    const float4 mk = *(const float4*)(tmk + c);
    const float4 mv = *(const float4*)(tmv + c);
    const float4 mr = *(const float4*)(tmr + c);
    const float* xp = (const float*)&xv;
    const float* pp = (const float*)&pv;
    const float* mkp = (const float*)&mk;
    const float* mvp = (const float*)&mv;
    const float* mrp = (const float*)&mr;
    ushort4 ko, vo, ro;
    unsigned short* kop = (unsigned short*)&ko;
    unsigned short* vop = (unsigned short*)&vo;
    unsigned short* rop = (unsigned short*)&ro;
#pragma unroll
    for (int q = 0; q < 4; ++q) {
      kop[q] = f2b(xp[q] * mkp[q] + pp[q] * (1.f - mkp[q]));
      vop[q] = f2b(xp[q] * mvp[q] + pp[q] * (1.f - mvp[q]));
      rop[q] = f2b(xp[q] * mrp[q] + pp[q] * (1.f - mrp[q]));
    }
    *(ushort4*)(kin + e) = ko;
    *(ushort4*)(vin + e) = vo;
    *(ushort4*)(rin + e) = ro;
  }
}

// ---------------- bf16 GEMM: C[M][N] = A[M][K] * W[N][K]^T ----------------
__global__ __launch_bounds__(256)
void gemm_bf16_bt(const unsigned short* __restrict__ A,
                  const unsigned short* __restrict__ W,
                  float* __restrict__ C_out,
                  int M, int N, int K) {
  constexpr int BM = 128, BN = 128, BK = 32;
  __shared__ alignas(16) unsigned short As[BM * BK];
  __shared__ alignas(16) unsigned short Bs[BN * BK];
  const int m0 = blockIdx.x * BM;
  const int n0 = blockIdx.y * BN;
  const int tid = threadIdx.x;
  const int lane = tid & 63;
  const int w = tid >> 6;
  const int wr = w >> 1, wc = w & 1;     // 2x2 wave grid, each wave 64x64
  const int fr = lane & 15;              // fragment row/col within 16
  const int fk = (lane >> 4) * 8;        // fragment K offset (8 contiguous)

  f32x4 acc[4][4];
#pragma unroll
  for (int i = 0; i < 4; ++i)
#pragma unroll
    for (int j = 0; j < 4; ++j) acc[i][j] = (f32x4){0.f, 0.f, 0.f, 0.f};

  for (int kt = 0; kt < K; kt += BK) {
#pragma unroll
    for (int j = 0; j < 2; ++j) {
      const int chunk = (w * 2 + j) * 64 + lane;  // 0..511
      const int row = chunk >> 2, cc = chunk & 3;
      const unsigned short* gsrcA = A + (size_t)(m0 + row) * K + kt + cc * 8;
      __builtin_amdgcn_global_load_lds(
          (const __attribute__((address_space(1))) void*)gsrcA,
          (__attribute__((address_space(3))) void*)&As[(w * 2 + j) * 512],
          16, 0, 0);
      const unsigned short* gsrcB = W + (size_t)(n0 + row) * K + kt + cc * 8;
      __builtin_amdgcn_global_load_lds(
          (const __attribute__((address_space(1))) void*)gsrcB,
          (__attribute__((address_space(3))) void*)&Bs[(w * 2 + j) * 512],
          16, 0, 0);
    }
    __syncthreads();

    short8 af[4], bfr[4];
#pragma unroll
    for (int i = 0; i < 4; ++i) {
      af[i]  = *(const short8*)&As[(wr * 64 + i * 16 + fr) * BK + fk];
      bfr[i] = *(const short8*)&Bs[(wc * 64 + i * 16 + fr) * BK + fk];
    }
#pragma unroll
    for (int i = 0; i < 4; ++i)
#pragma unroll
      for (int j = 0; j < 4; ++j)
        acc[i][j] = __builtin_amdgcn_mfma_f32_16x16x32_bf16(af[i], bfr[j],
                                                            acc[i][j], 0, 0, 0);
    __syncthreads();
  }

  const int orow = (lane >> 4) * 4;
  const int ocol = lane & 15;
#pragma unroll
  for (int i = 0; i < 4; ++i)
#pragma unroll
    for (int j = 0; j < 4; ++j) {
      const size_t rbase = (size_t)(m0 + wr * 64 + i * 16 + orow);
      const int cb = n0 + wc * 64 + j * 16 + ocol;
#pragma unroll
      for (int q = 0; q < 4; ++q)
        C_out[(rbase + q) * N + cb] = acc[i][j][q];
    }
}

// ---------------- WKV chunked scan ----------------
// State (num, den, mx) represents N = num*e^mx, D = den*e^mx with
// N' = e^w N + e^{k} v per step. Chunk of length L: N_out = e^{Lw} N_in + N_loc.

// Phase 1: per-chunk local states. g encodes [b][chunk j][c].
__global__ void wkv_phase1(const float* __restrict__ key,
                           const float* __restrict__ val,
                           const float* __restrict__ td,
                           float* __restrict__ s_num,
                           float* __restrict__ s_den,
                           float* __restrict__ s_mx) {
  const int g = blockIdx.x * blockDim.x + threadIdx.x;  // [0, B*NCH*C)
  const int c = g & (Cc - 1);
  const int j = (g / Cc) & (WKV_NCH - 1);
  const int b = g / (Cc * WKV_NCH);
  const float w = -__expf(td[c]);
  float num = 0.f, den = 0.f, mx = -1e38f;
  size_t idx = ((size_t)b * Tc + (size_t)j * WKV_L) * Cc + c;
#pragma unroll 4
  for (int i = 0; i < WKV_L; ++i, idx += Cc) {
    const float kt = key[idx], vt = val[idx];
    const float mw = mx + w;
    const float mn = fmaxf(mw, kt);
    const float a1 = __expf(mw - mn);
    const float a2 = __expf(kt - mn);
    num = a1 * num + a2 * vt;
    den = a1 * den + a2;
    mx = mn;
  }
  s_num[g] = num; s_den[g] = den; s_mx[g] = mx;
}

// Phase 2: exclusive scan over chunk states per (b,c); in-place -> incoming states.
__global__ void wkv_phase2(const float* __restrict__ td,
                           float* __restrict__ s_num,
                           float* __restrict__ s_den,
                           float* __restrict__ s_mx) {
  const int g = blockIdx.x * blockDim.x + threadIdx.x;  // [0, B*C)
  const int c = g & (Cc - 1);
  const int b = g / Cc;
  const float Lw = -__expf(td[c]) * (float)WKV_L;
  float num = 0.f, den = 0.f, mx = -1e38f;
  size_t base = (size_t)b * WKV_NCH * Cc + c;
  for (int j = 0; j < WKV_NCH; ++j) {
    const size_t s = base + (size_t)j * Cc;
    const float ln = s_num[s], ld = s_den[s], lm = s_mx[s];
    s_num[s] = num; s_den[s] = den; s_mx[s] = mx;  // exclusive prefix
    const float md = mx + Lw;
    const float m = fmaxf(md, lm);
    const float e1 = __expf(md - m);
    const float e2 = __expf(lm - m);
    num = e1 * num + e2 * ln;
    den = e1 * den + e2 * ld;
    mx = m;
  }
}

// Phase 3: outputs within each chunk from incoming state; fused sigmoid gate.
__global__ void wkv_phase3(const float* __restrict__ key,
                           const float* __restrict__ val,
                           const float* __restrict__ rec,
                           const float* __restrict__ td,
                           const float* __restrict__ tf,
                           const float* __restrict__ s_num,
                           const float* __restrict__ s_den,
                           const float* __restrict__ s_mx,
                           unsigned short* __restrict__ rwkv) {
  const int g = blockIdx.x * blockDim.x + threadIdx.x;  // [0, B*NCH*C)
  const int c = g & (Cc - 1);
  const int j = (g / Cc) & (WKV_NCH - 1);
  const int b = g / (Cc * WKV_NCH);
  const float w = -__expf(td[c]);
  const float u = tf[c];
  float num = s_num[g], den = s_den[g], mx = s_mx[g];
  size_t idx = ((size_t)b * Tc + (size_t)j * WKV_L) * Cc + c;
#pragma unroll 2
  for (int i = 0; i < WKV_L; ++i, idx += Cc) {
    const float kt = key[idx];
    const float vt = val[idx];
    const float rt = rec[idx];
    const float ku = kt + u;
    const float mo = fmaxf(mx, ku);
    const float e1 = __expf(mx - mo);
    const float e2 = __expf(ku - mo);
    const float out = (e1 * num + e2 * vt) / (e1 * den + e2);
    const float sr = 1.f / (1.f + __expf(-rt));
    rwkv[idx] = f2b(sr * out);
    const float mw = mx + w;
    const float mn = fmaxf(mw, kt);
    const float a1 = __expf(mw - mn);
    const float a2 = __expf(kt - mn);
    num = a1 * num + a2 * vt;
    den = a1 * den + a2;
    mx = mn;
  }
}

extern "C" void kernel_launch(void* const* d_in, const int* in_sizes, int n_in,
                              void* d_out, int out_size, void* d_ws, size_t ws_size,
                              hipStream_t stream) {
  const float* x   = (const float*)d_in[0];
  const float* Wk  = (const float*)d_in[1];
  const float* Wv  = (const float*)d_in[2];
  const float* Wr  = (const float*)d_in[3];
  const float* Wo  = (const float*)d_in[4];
  const float* td  = (const float*)d_in[5];
  const float* tf  = (const float*)d_in[6];
  const float* tmk = (const float*)d_in[7];
  const float* tmv = (const float*)d_in[8];
  const float* tmr = (const float*)d_in[9];

  const long BT = (long)Bc * Tc;     // 16384
  const long NE = BT * Cc;           // 16,777,216
  const long CC = (long)Cc * Cc;     // 1,048,576

  // Workspace carve (~232 MB total)
  char* p = (char*)d_ws;
  unsigned short* Wk_b = (unsigned short*)p; p += CC * 2;
  unsigned short* Wv_b = (unsigned short*)p; p += CC * 2;
  unsigned short* Wr_b = (unsigned short*)p; p += CC * 2;
  unsigned short* Wo_b = (unsigned short*)p; p += CC * 2;
  unsigned short* kin  = (unsigned short*)p; p += NE * 2;
  unsigned short* vin  = (unsigned short*)p; p += NE * 2;
  unsigned short* rin  = (unsigned short*)p; p += NE * 2;
  float* keyf = (float*)p; p += NE * 4;
  float* valf = (float*)p; p += NE * 4;
  // receptance f32 lives in d_out (dead before final GEMM overwrites it)
  float* recf = (float*)d_out;
  unsigned short* rwkv = rin;       // rin dead after receptance GEMM
  // chunk-state arrays alias kin (dead after key GEMM): 3 x 2MB within 32MB
  const long NS = (long)Bc * WKV_NCH * Cc;  // 524288
  float* s_num = (float*)kin;
  float* s_den = s_num + NS;
  float* s_mx  = s_den + NS;

  // 1. weights -> bf16
  {
    const int n4 = (int)(CC / 4);
    dim3 g((n4 + 255) / 256), b_(256);
    convert_bf16_kernel<<<g, b_, 0, stream>>>(Wk, Wk_b, n4);
    convert_bf16_kernel<<<g, b_, 0, stream>>>(Wv, Wv_b, n4);
    convert_bf16_kernel<<<g, b_, 0, stream>>>(Wr, Wr_b, n4);
    convert_bf16_kernel<<<g, b_, 0, stream>>>(Wo, Wo_b, n4);
  }

  // 2. time-mix + cast
  mix3_kernel<<<2048, 256, 0, stream>>>(x, tmk, tmv, tmr, kin, vin, rin, NE / 4);

  // 3. QKV-style GEMMs
  {
    dim3 grid((unsigned)(BT / 128), (unsigned)(Cc / 128)), blk(256);
    gemm_bf16_bt<<<grid, blk, 0, stream>>>(kin, Wk_b, keyf, (int)BT, Cc, Cc);
    gemm_bf16_bt<<<grid, blk, 0, stream>>>(vin, Wv_b, valf, (int)BT, Cc, Cc);
    gemm_bf16_bt<<<grid, blk, 0, stream>>>(rin, Wr_b, recf, (int)BT, Cc, Cc);
  }

  // 4. WKV chunked scan + sigmoid gate -> rwkv bf16
  {
    const int nth = (int)NS;                    // 524288
    wkv_phase1<<<nth / 256, 256, 0, stream>>>(keyf, valf, td, s_num, s_den, s_mx);
    wkv_phase2<<<(Bc * Cc) / 256, 256, 0, stream>>>(td, s_num, s_den, s_mx);
    wkv_phase3<<<nth / 256, 256, 0, stream>>>(keyf, valf, recf, td, tf,
                                              s_num, s_den, s_mx, rwkv);
  }

  // 5. output GEMM -> d_out
  {
    dim3 grid((unsigned)(BT / 128), (unsigned)(Cc / 128)), blk(256);
    gemm_bf16_bt<<<grid, blk, 0, stream>>>(rwkv, Wo_b, (float*)d_out, (int)BT, Cc, Cc);
  }
}